// Round 7
// baseline (705.917 us; speedup 1.0000x reference)
//
#include <hip/hip_runtime.h>
#include <hip/hip_bf16.h>
#include <math.h>

namespace {

constexpr int kB = 2, kS = 1024, kE = 1024, kH = 16, kD = 64, kV = 32000, kFH = 512;
constexpr int kBS = kB * kS;   // 2048 rows
constexpr int kHD = kH * kD;   // 1024

typedef __attribute__((ext_vector_type(8))) short bf16x8;
typedef __attribute__((ext_vector_type(4))) float f32x4;

#define GLDS(g, l) __builtin_amdgcn_global_load_lds(                          \
      (const __attribute__((address_space(1))) void*)(g),                     \
      (__attribute__((address_space(3))) void*)(l), 16, 0, 0)

// ---------------- positional-encoding table: pe[s][e], s<kS ----------------
__global__ __launch_bounds__(256) void pe_table_k(float* __restrict__ pe) {
  int s = blockIdx.x;
  float* dst = pe + (size_t)s * kE;
  for (int e = threadIdx.x; e < kE; e += 256) {
    int i = e >> 1;
    float denom = powf(10000.0f, (float)(2 * i) * (1.0f / (float)kE));
    float ang = (float)s / denom;
    dst[e] = (e & 1) ? cosf(ang) : sinf(ang);
  }
}

// ---------------- embedding + PE (dual fp32/bf16 out) ----------------
__global__ __launch_bounds__(256) void embed_pe_k(const int* __restrict__ tok,
                                                  const float* __restrict__ emb,
                                                  const float* __restrict__ pe,
                                                  float* __restrict__ out,
                                                  __hip_bfloat16* __restrict__ outb) {
  int row = blockIdx.x;              // b*S + s
  int s = row & (kS - 1);
  int t = tok[row];
  const float4* src = (const float4*)(emb + (size_t)t * kE);
  const float4* per = (const float4*)(pe + (size_t)s * kE);
  float4* dst = (float4*)(out + (size_t)row * kE);
  __hip_bfloat16* dstb = outb + (size_t)row * kE;
  for (int e4 = threadIdx.x; e4 < kE / 4; e4 += 256) {
    float4 a = src[e4], p = per[e4];
    float4 v = make_float4(a.x + p.x, a.y + p.y, a.z + p.z, a.w + p.w);
    dst[e4] = v;
    union { __hip_bfloat16 h[4]; short4 s4; } u;
    u.h[0] = __float2bfloat16(v.x); u.h[1] = __float2bfloat16(v.y);
    u.h[2] = __float2bfloat16(v.z); u.h[3] = __float2bfloat16(v.w);
    ((short4*)dstb)[e4] = u.s4;
  }
}

// ---------------- transpose + cast: src[R,C] fp32 -> dst[C,R] bf16 (batched) -------
__global__ __launch_bounds__(256) void tcast_k(const float* __restrict__ src,
                                               __hip_bfloat16* __restrict__ dst,
                                               int R, int C) {
  __shared__ float tile[32][33];
  src += (size_t)blockIdx.z * R * C;
  dst += (size_t)blockIdx.z * R * C;
  int c0 = blockIdx.x * 32, r0 = blockIdx.y * 32;
  int tx = threadIdx.x & 31, ty = threadIdx.x >> 5;   // ty in 0..7
#pragma unroll
  for (int i = 0; i < 32; i += 8)
    tile[ty + i][tx] = src[(size_t)(r0 + ty + i) * C + c0 + tx];
  __syncthreads();
#pragma unroll
  for (int i = 0; i < 32; i += 8)
    dst[(size_t)(c0 + ty + i) * R + r0 + tx] = __float2bfloat16(tile[tx][ty + i]);
}

// ---------------- bf16 transpose per head: v[BS, sV] -> vt[(b*H+h)*64 + d][S] ------
__global__ __launch_bounds__(256) void vtrans_k(const __hip_bfloat16* __restrict__ v,
                                                int sV, __hip_bfloat16* __restrict__ vt) {
  __shared__ unsigned short tile[32][34];
  int s0 = blockIdx.x * 32, d0 = blockIdx.y * 32, bh = blockIdx.z;
  int b = bh >> 4, h = bh & 15;
  int tx = threadIdx.x & 31, ty = threadIdx.x >> 5;
  const unsigned short* src = (const unsigned short*)v;
  unsigned short* dst = (unsigned short*)vt;
#pragma unroll
  for (int i = 0; i < 32; i += 8)
    tile[ty + i][tx] = src[(size_t)(b * kS + s0 + ty + i) * sV + h * 64 + d0 + tx];
  __syncthreads();
#pragma unroll
  for (int i = 0; i < 32; i += 8)
    dst[(size_t)(bh * 64 + d0 + ty + i) * kS + s0 + tx] = tile[tx][ty + i];
}

// ---------------- 128x128 bf16 GEMM, 3-buffer BK=32 counted-vmcnt pipeline ---------
// mode: 0 = fp32 out, 1 = fp32+relu, 2 = bf16 out, 3 = bf16+relu
__global__ __launch_bounds__(256) void gemm_bf16_k(
    const __hip_bfloat16* __restrict__ A,   // [M,K] bf16
    const __hip_bfloat16* __restrict__ Bt,  // [N,K] bf16
    const float* __restrict__ bias,         // [N]
    void* __restrict__ Cout,
    int N, int K, int mode, int gridM) {
  __shared__ __align__(16) char L[3][16384];   // per buf: A 8KB | B 8KB
  const int nwg = gridDim.x, id = blockIdx.x;
  const int swz = (id & 7) * (nwg >> 3) + (id >> 3);
  const int bm = (swz % gridM) * 128, bn = (swz / gridM) * 128;
  const int tid = threadIdx.x, w = tid >> 6, lane = tid & 63;
  const int wr = w >> 1, wc = w & 1;
  const int lr = lane & 15, kg = lane >> 4;
  const int NT = K >> 5;
  const __hip_bfloat16* Ag = A + (size_t)bm * K;
  const __hip_bfloat16* Bg = Bt + (size_t)bn * K;

  auto stage = [&](int t) {   // 4 loads/thread (A 2 + B 2)
    const int buf = t % 3, k0 = t * 32;
#pragma unroll
    for (int j = 0; j < 2; ++j) {
      int slot = w * 64 + lane + j * 256;          // 0..511 (16B slots)
      int row = slot >> 2;
      int cs = (slot & 3) ^ ((row >> 1) & 3);      // inverse swizzle on source
      GLDS(Ag + (size_t)row * K + k0 + cs * 8, L[buf] + w * 1024 + j * 4096);
      GLDS(Bg + (size_t)row * K + k0 + cs * 8, L[buf] + 8192 + w * 1024 + j * 4096);
    }
  };

  f32x4 acc[4][4] = {};
  stage(0);
  stage(1);
  asm volatile("s_waitcnt vmcnt(4)" ::: "memory");
  __builtin_amdgcn_s_barrier();

  for (int t = 0; t < NT; ++t) {
    const char* buf = L[t % 3];
    if (t + 2 < NT) stage(t + 2);
    bf16x8 af[4], bfr[4];
#pragma unroll
    for (int i = 0; i < 4; ++i) {
      int row = wr * 64 + i * 16 + lr;
      af[i] = *(const bf16x8*)(buf + row * 64 + ((kg ^ ((row >> 1) & 3)) << 4));
    }
#pragma unroll
    for (int j = 0; j < 4; ++j) {
      int row = wc * 64 + j * 16 + lr;
      bfr[j] = *(const bf16x8*)(buf + 8192 + row * 64 + ((kg ^ ((row >> 1) & 3)) << 4));
    }
    __builtin_amdgcn_s_setprio(1);
#pragma unroll
    for (int i = 0; i < 4; ++i)
#pragma unroll
      for (int j = 0; j < 4; ++j)
        acc[i][j] = __builtin_amdgcn_mfma_f32_16x16x32_bf16(af[i], bfr[j], acc[i][j], 0, 0, 0);
    __builtin_amdgcn_s_setprio(0);
    if (t + 2 < NT)
      asm volatile("s_waitcnt vmcnt(4) lgkmcnt(0)" ::: "memory");
    else
      asm volatile("s_waitcnt vmcnt(0) lgkmcnt(0)" ::: "memory");
    __builtin_amdgcn_s_barrier();
  }

  float* Cf = (float*)Cout;
  __hip_bfloat16* Cb = (__hip_bfloat16*)Cout;
#pragma unroll
  for (int j = 0; j < 4; ++j) {
    int col = bn + wc * 64 + j * 16 + lr;
    float bc = bias[col];
#pragma unroll
    for (int i = 0; i < 4; ++i) {
      int rbase = bm + wr * 64 + i * 16 + kg * 4;
#pragma unroll
      for (int r = 0; r < 4; ++r) {
        float val = acc[i][j][r] + bc;
        if (mode & 1) val = fmaxf(val, 0.0f);
        if (mode < 2) Cf[(size_t)(rbase + r) * N + col] = val;
        else          Cb[(size_t)(rbase + r) * N + col] = __float2bfloat16(val);
      }
    }
  }
}

// ---------------- 128x256 bf16 GEMM, 3-buffer BK=32, 2 blocks/CU (vocab) ----------
// 8 waves (2M x 4N, wave tile 64x64). LDS/buf: A 8KB + B 16KB = 24KB; x3 = 72KB.
// 3 loads/thread/tile -> steady-state vmcnt(3).
__global__ __launch_bounds__(512, 4) void gemm256_k(
    const __hip_bfloat16* __restrict__ A,   // [M,K]
    const __hip_bfloat16* __restrict__ Bt,  // [N,K]
    const float* __restrict__ bias,
    float* __restrict__ C,
    int N, int K, int gridM) {
  __shared__ __align__(16) char L[3][24576];   // per buf: A 8KB | B 16KB
  const int tid = threadIdx.x, w = tid >> 6, lane = tid & 63;
  const int wr = w >> 2, wc = w & 3;
  const int lr = lane & 15, kg = lane >> 4;
  const int nwg = gridDim.x, id = blockIdx.x;
  const int swz = (id & 7) * (nwg >> 3) + (id >> 3);
  const int bm = (swz % gridM) * 128, bn = (swz / gridM) * 256;
  const int NT = K >> 5;
  const __hip_bfloat16* Ag = A + (size_t)bm * K;
  const __hip_bfloat16* Bg = Bt + (size_t)bn * K;

  auto stage = [&](int t) {   // 3 loads/thread: A 1 + B 2
    const int buf = t % 3, k0 = t * 32;
    {
      int slot = tid;                              // 0..511
      int row = slot >> 2;                         // 0..127
      int cs = (slot & 3) ^ ((row >> 1) & 3);
      GLDS(Ag + (size_t)row * K + k0 + cs * 8, L[buf] + tid * 16);
    }
#pragma unroll
    for (int j = 0; j < 2; ++j) {
      int slot = tid + j * 512;                    // 0..1023
      int row = slot >> 2;                         // 0..255
      int cs = (slot & 3) ^ ((row >> 1) & 3);
      GLDS(Bg + (size_t)row * K + k0 + cs * 8, L[buf] + 8192 + slot * 16);
    }
  };

  f32x4 acc[4][4] = {};
  stage(0);
  stage(1);
  asm volatile("s_waitcnt vmcnt(3)" ::: "memory");
  __builtin_amdgcn_s_barrier();

  for (int t = 0; t < NT; ++t) {
    const char* buf = L[t % 3];
    if (t + 2 < NT) stage(t + 2);
    bf16x8 af[4], bfr[4];
#pragma unroll
    for (int i = 0; i < 4; ++i) {
      int row = wr * 64 + i * 16 + lr;
      af[i] = *(const bf16x8*)(buf + row * 64 + ((kg ^ ((row >> 1) & 3)) << 4));
    }
#pragma unroll
    for (int j = 0; j < 4; ++j) {
      int row = wc * 64 + j * 16 + lr;
      bfr[j] = *(const bf16x8*)(buf + 8192 + row * 64 + ((kg ^ ((row >> 1) & 3)) << 4));
    }
    __builtin_amdgcn_s_setprio(1);
#pragma unroll
    for (int i = 0; i < 4; ++i)
#pragma unroll
      for (int j = 0; j < 4; ++j)
        acc[i][j] = __builtin_amdgcn_mfma_f32_16x16x32_bf16(af[i], bfr[j], acc[i][j], 0, 0, 0);
    __builtin_amdgcn_s_setprio(0);
    if (t + 2 < NT)
      asm volatile("s_waitcnt vmcnt(3) lgkmcnt(0)" ::: "memory");
    else
      asm volatile("s_waitcnt vmcnt(0) lgkmcnt(0)" ::: "memory");
    __builtin_amdgcn_s_barrier();
  }

  // epilogue
#pragma unroll
  for (int j = 0; j < 4; ++j) {
    int col = bn + wc * 64 + j * 16 + lr;
    float bc = bias[col];
#pragma unroll
    for (int i = 0; i < 4; ++i) {
      int rbase = bm + wr * 64 + i * 16 + (kg << 2);
#pragma unroll
      for (int r = 0; r < 4; ++r)
        C[(size_t)(rbase + r) * N + col] = acc[i][j][r] + bc;
    }
  }
}

// ---------------- MFMA flash attention ----------------
__global__ __launch_bounds__(256) void attn_mfma_k(
    const __hip_bfloat16* __restrict__ q, int sQ,
    const __hip_bfloat16* __restrict__ k, int sK,
    const __hip_bfloat16* __restrict__ vt,   // [(b*H+h)*64 + d][S]
    __hip_bfloat16* __restrict__ o,          // [BS][HD]
    int causal) {
  __shared__ __align__(16) char Ks[8192];
  __shared__ __align__(16) char Vs[8192];
  __shared__ __align__(16) char Ps[4][2304];   // per-wave P tile [16 q][72 bf16]
  const int tid = threadIdx.x, w = tid >> 6, l = tid & 63;
  const int lr = l & 15, lg = l >> 4;
  const int q0 = blockIdx.x * 64, h = blockIdx.y, b = blockIdx.z;

  const int qrow = q0 + w * 16 + lr;
  const __hip_bfloat16* qp = q + (size_t)(b * kS + qrow) * sQ + h * 64 + lg * 8;
  bf16x8 aQ0 = *(const bf16x8*)qp;
  bf16x8 aQ1 = *(const bf16x8*)(qp + 32);

  f32x4 oacc[4] = {};
  float mrun[4], lrun[4];
#pragma unroll
  for (int r = 0; r < 4; ++r) { mrun[r] = -INFINITY; lrun[r] = 0.0f; }

  const int ntiles = causal ? ((q0 >> 6) + 1) : (kS >> 6);
  const int diagT = causal ? (q0 >> 6) : -1;
  const char* kbase = (const char*)(k + (size_t)(b * kS) * sK + h * 64);
  const char* vbase = (const char*)(vt + (size_t)((b * kH + h) * 64) * kS);
  char* Pw = Ps[w];

  for (int t = 0; t < ntiles; ++t) {
    const int kv0 = t * 64;
    __syncthreads();
#pragma unroll
    for (int i = 0; i < 2; ++i) {
      int slot = w * 128 + i * 64 + l;
      int row = slot >> 3, sl = slot & 7, c = sl ^ (row & 7);
      const char* gk = kbase + (size_t)(kv0 + row) * sK * 2 + c * 16;
      const char* gv = vbase + (size_t)row * kS * 2 + kv0 * 2 + c * 16;
      GLDS(gk, Ks + (w * 128 + i * 64) * 16);
      GLDS(gv, Vs + (w * 128 + i * 64) * 16);
    }
    __syncthreads();

    // ---- S = Q @ K^T ----
    f32x4 sacc[4] = {};
#pragma unroll
    for (int nf = 0; nf < 4; ++nf) {
      int key = nf * 16 + lr;
#pragma unroll
      for (int kf = 0; kf < 2; ++kf) {
        int ch = (lg + kf * 4) ^ (key & 7);
        bf16x8 bK = *(const bf16x8*)(Ks + key * 128 + ch * 16);
        sacc[nf] = __builtin_amdgcn_mfma_f32_16x16x32_bf16(kf ? aQ1 : aQ0, bK, sacc[nf], 0, 0, 0);
      }
    }

    // ---- online softmax ----
#pragma unroll
    for (int r = 0; r < 4; ++r) {
      int row16 = lg * 4 + r;
      int qg = q0 + w * 16 + row16;
      float sv[4];
#pragma unroll
      for (int nf = 0; nf < 4; ++nf) {
        float s = sacc[nf][r] * 0.125f;
        if (t == diagT && (kv0 + nf * 16 + lr) > qg) s = -INFINITY;
        sv[nf] = s;
      }
      float mx = fmaxf(fmaxf(sv[0], sv[1]), fmaxf(sv[2], sv[3]));
#pragma unroll
      for (int m = 1; m < 16; m <<= 1) mx = fmaxf(mx, __shfl_xor(mx, m));
      float mnew = fmaxf(mrun[r], mx);
      float sc = __expf(mrun[r] - mnew);
      mrun[r] = mnew;
      float rs = 0.0f;
#pragma unroll
      for (int nf = 0; nf < 4; ++nf) {
        float p = __expf(sv[nf] - mnew);
        rs += p;
        *(__hip_bfloat16*)(Pw + row16 * 144 + (nf * 16 + lr) * 2) = __float2bfloat16(p);
      }
#pragma unroll
      for (int m = 1; m < 16; m <<= 1) rs += __shfl_xor(rs, m);
      lrun[r] = lrun[r] * sc + rs;
#pragma unroll
      for (int nfd = 0; nfd < 4; ++nfd) oacc[nfd][r] *= sc;
    }

    // ---- O += P @ V ----
    bf16x8 aP0 = *(const bf16x8*)(Pw + lr * 144 + (lg * 8) * 2);
    bf16x8 aP1 = *(const bf16x8*)(Pw + lr * 144 + (lg * 8 + 32) * 2);
#pragma unroll
    for (int nfd = 0; nfd < 4; ++nfd) {
      int d = nfd * 16 + lr;
#pragma unroll
      for (int kf = 0; kf < 2; ++kf) {
        int ch = (lg + kf * 4) ^ (d & 7);
        bf16x8 bV = *(const bf16x8*)(Vs + d * 128 + ch * 16);
        oacc[nfd] = __builtin_amdgcn_mfma_f32_16x16x32_bf16(kf ? aP1 : aP0, bV, oacc[nfd], 0, 0, 0);
      }
    }
  }

#pragma unroll
  for (int r = 0; r < 4; ++r) {
    float inv = 1.0f / lrun[r];
    int rowg = q0 + w * 16 + lg * 4 + r;
#pragma unroll
    for (int nfd = 0; nfd < 4; ++nfd)
      o[(size_t)(b * kS + rowg) * kHD + h * 64 + nfd * 16 + lr] =
          __float2bfloat16(oacc[nfd][r] * inv);
  }
}

// ---------------- residual + LayerNorm (dual fp32/bf16 out, float4) ----------------
__global__ __launch_bounds__(256) void ln_res_k(const float* __restrict__ a,
                                                const float* __restrict__ b,
                                                const float* __restrict__ gamma,
                                                const float* __restrict__ beta,
                                                float* __restrict__ out,
                                                __hip_bfloat16* __restrict__ outb) {
  __shared__ float sh[10];
  int row = blockIdx.x, tid = threadIdx.x;
  const float4* a4 = (const float4*)(a + (size_t)row * kE);
  const float4* b4 = (const float4*)(b + (size_t)row * kE);
  float4 t = a4[tid], u = b4[tid];
  t.x += u.x; t.y += u.y; t.z += u.z; t.w += u.w;
  float s = t.x + t.y + t.z + t.w;
  float q2 = t.x * t.x + t.y * t.y + t.z * t.z + t.w * t.w;
  for (int o = 32; o > 0; o >>= 1) { s += __shfl_down(s, o); q2 += __shfl_down(q2, o); }
  int lane = tid & 63, wid = tid >> 6;
  if (lane == 0) { sh[wid] = s; sh[4 + wid] = q2; }
  __syncthreads();
  if (tid == 0) {
    float S2 = sh[0] + sh[1] + sh[2] + sh[3];
    float Q2 = sh[4] + sh[5] + sh[6] + sh[7];
    float mean = S2 * (1.0f / kE);
    float var = Q2 * (1.0f / kE) - mean * mean;
    sh[8] = mean;
    sh[9] = rsqrtf(var + 1e-15f);
  }
  __syncthreads();
  float mean = sh[8], inv = sh[9];
  float4 g = ((const float4*)gamma)[tid], be = ((const float4*)beta)[tid];
  float4 v;
  v.x = g.x * ((t.x - mean) * inv) + be.x;
  v.y = g.y * ((t.y - mean) * inv) + be.y;
  v.z = g.z * ((t.z - mean) * inv) + be.z;
  v.w = g.w * ((t.w - mean) * inv) + be.w;
  ((float4*)(out + (size_t)row * kE))[tid] = v;
  union { __hip_bfloat16 h[4]; short4 s4; } uo;
  uo.h[0] = __float2bfloat16(v.x); uo.h[1] = __float2bfloat16(v.y);
  uo.h[2] = __float2bfloat16(v.z); uo.h[3] = __float2bfloat16(v.w);
  ((short4*)(outb + (size_t)row * kE))[tid] = uo.s4;
}

// ---------------- row softmax over V (in place, register-resident single pass) -----
__global__ __launch_bounds__(512) void softmax_rows_k(float* __restrict__ x) {
  __shared__ float sh[18];
  int row = blockIdx.x;
  float4* x4 = (float4*)(x + (size_t)row * kV);
  const int n4 = kV / 4;   // 8000
  int tid = threadIdx.x;
  float4 v[16];
  float m = -INFINITY, sum = 0.0f;
#pragma unroll
  for (int i = 0; i < 16; ++i) {
    int idx = tid + i * 512;
    if (idx < n4) {
      v[i] = x4[idx];
      float mx = fmaxf(fmaxf(v[i].x, v[i].y), fmaxf(v[i].z, v[i].w));
      float nm = fmaxf(m, mx);
      sum = sum * __expf(m - nm) + __expf(v[i].x - nm) + __expf(v[i].y - nm) +
            __expf(v[i].z - nm) + __expf(v[i].w - nm);
      m = nm;
    }
  }
  for (int o = 32; o > 0; o >>= 1) {
    float om = __shfl_down(m, o), os = __shfl_down(sum, o);
    float nm = fmaxf(m, om);
    sum = sum * __expf(m - nm) + os * __expf(om - nm);
    m = nm;
  }
  int lane = tid & 63, wid = tid >> 6;
  if (lane == 0) { sh[wid] = m; sh[8 + wid] = sum; }
  __syncthreads();
  if (tid == 0) {
    float M = sh[0], S2 = 0.0f;
#pragma unroll
    for (int i2 = 1; i2 < 8; ++i2) M = fmaxf(M, sh[i2]);
#pragma unroll
    for (int i2 = 0; i2 < 8; ++i2) S2 += sh[8 + i2] * __expf(sh[i2] - M);
    sh[16] = M;
    sh[17] = 1.0f / S2;
  }
  __syncthreads();
  float M = sh[16], rcp = sh[17];
#pragma unroll
  for (int i = 0; i < 16; ++i) {
    int idx = tid + i * 512;
    if (idx < n4) {
      float4 o2;
      o2.x = __expf(v[i].x - M) * rcp;
      o2.y = __expf(v[i].y - M) * rcp;
      o2.z = __expf(v[i].z - M) * rcp;
      o2.w = __expf(v[i].w - M) * rcp;
      x4[idx] = o2;
    }
  }
}

}  // namespace

extern "C" void kernel_launch(void* const* d_in, const int* in_sizes, int n_in,
                              void* d_out, int out_size, void* d_ws, size_t ws_size,
                              hipStream_t stream) {
  const int*   src    = (const int*)d_in[0];
  const int*   trg    = (const int*)d_in[1];
  const float* emb_e  = (const float*)d_in[2];
  const float* emb_d  = (const float*)d_in[3];
  const float* qkv_e  = (const float*)d_in[4];
  const float* bqkv_e = (const float*)d_in[5];
  const float* wo_e   = (const float*)d_in[6];
  const float* bo_e   = (const float*)d_in[7];
  const float* qkv_m  = (const float*)d_in[8];
  const float* bqkv_m = (const float*)d_in[9];
  const float* wo_m   = (const float*)d_in[10];
  const float* bo_m   = (const float*)d_in[11];
  const float* qkv_c  = (const float*)d_in[12];
  const float* bqkv_c = (const float*)d_in[13];
  const float* wo_c   = (const float*)d_in[14];
  const float* bo_c   = (const float*)d_in[15];
  const float* gamma  = (const float*)d_in[16];
  const float* beta   = (const float*)d_in[17];
  const float* ffw1   = (const float*)d_in[18];
  const float* ffb1   = (const float*)d_in[19];
  const float* ffw2   = (const float*)d_in[20];
  const float* ffb2   = (const float*)d_in[21];
  const float* wout   = (const float*)d_in[22];
  const float* bout   = (const float*)d_in[23];
  float* out = (float*)d_out;

  float* w = (float*)d_ws;
  const size_t R = (size_t)kBS * kE;   // 2M elements
  float* enc_x = w + 0 * R;            // reused as n2d
  float* dec_x = w + 1 * R;            // reused as n3d
  float* t1    = w + 2 * R;
  float* n1    = w + 3 * R;            // reused as n1d
  float* n_enc = w + 4 * R;
  __hip_bfloat16* bb     = (__hip_bfloat16*)(w + 5 * R);
  __hip_bfloat16* enc_xb = bb;                       // R
  __hip_bfloat16* dec_xb = enc_xb + R;               // R
  __hip_bfloat16* n1b    = dec_xb + R;               // R
  __hip_bfloat16* n_encb = n1b + R;                  // R
  __hip_bfloat16* qkvb   = n_encb + R;               // 3R   [BS, 3HD]
  __hip_bfloat16* kvb    = qkvb + 3 * R;             // 2R   [BS, 2HD]
  __hip_bfloat16* qb1    = kvb + 2 * R;              // R    [BS, HD]
  __hip_bfloat16* vtb    = qb1 + R;                  // R    [B*H*64, S]
  __hip_bfloat16* ao16   = vtb + R;                  // R
  __hip_bfloat16* ffhb   = ao16 + R;                 // R/2
  __hip_bfloat16* Wqkv   = ffhb + R / 2;             // 1.5R  [3HD, E]
  __hip_bfloat16* Wo     = Wqkv + (size_t)3 * kHD * kE;
  __hip_bfloat16* Wf1 = Wo + (size_t)kE * kHD;       // [FH, E]
  __hip_bfloat16* Wf2 = Wf1 + (size_t)kFH * kE;      // [E, FH]
  __hip_bfloat16* Wv  = Wf2 + (size_t)kE * kFH;      // [V, E]
  float* pe = (float*)Wv;   // alias: PE table used before Wv is written

  auto tcast = [&](const float* s, __hip_bfloat16* d, int Rr, int Cc, int batch) {
    tcast_k<<<dim3(Cc / 32, Rr / 32, batch), 256, 0, stream>>>(s, d, Rr, Cc);
  };
  auto gemmb = [&](const __hip_bfloat16* A, const __hip_bfloat16* Bt, const float* bias,
                   void* C, int M, int N, int K, int mode) {
    int gridM = M / 128;
    gemm_bf16_k<<<dim3(gridM * (N / 128)), 256, 0, stream>>>(A, Bt, bias, C, N, K, mode, gridM);
  };
  auto vtrans = [&](const __hip_bfloat16* v, int sV) {
    vtrans_k<<<dim3(kS / 32, kD / 32, kB * kH), 256, 0, stream>>>(v, sV, vtb);
  };
  auto attn = [&](const __hip_bfloat16* q, int sQ, const __hip_bfloat16* k, int sK,
                  int causal) {
    attn_mfma_k<<<dim3(kS / 64, kH, kB), 256, 0, stream>>>(q, sQ, k, sK, vtb, ao16, causal);
  };
  auto ln = [&](const float* a, const float* b2, int sel, float* o1, __hip_bfloat16* o2) {
    ln_res_k<<<kBS, 256, 0, stream>>>(a, b2, gamma + sel * kE, beta + sel * kE, o1, o2);
  };

  pe_table_k<<<kS, 256, 0, stream>>>(pe);

  // ---------------- encoder ----------------
  embed_pe_k<<<kBS, 256, 0, stream>>>(src, emb_e, pe, enc_x, enc_xb);
  tcast(qkv_e, Wqkv, kE, kD, 3 * kH);
  tcast(wo_e, Wo, kHD, kE, 1);
  gemmb(enc_xb, Wqkv, bqkv_e, qkvb, kBS, 3 * kHD, kE, 2);
  vtrans(qkvb + 2 * kHD, 3 * kHD);
  attn(qkvb, 3 * kHD, qkvb + kHD, 3 * kHD, 0);
  gemmb(ao16, Wo, bo_e, t1, kBS, kE, kHD, 0);
  ln(enc_x, t1, 0, n1, n1b);
  tcast(ffw1, Wf1, kE, kFH, 1);
  tcast(ffw2, Wf2, kFH, kE, 1);
  gemmb(n1b, Wf1, ffb1, ffhb, kBS, kFH, kE, 3);
  gemmb(ffhb, Wf2, ffb2, t1, kBS, kE, kFH, 0);
  ln(n1, t1, 1, n_enc, n_encb);

  // ---------------- decoder ----------------
  embed_pe_k<<<kBS, 256, 0, stream>>>(trg, emb_d, pe, dec_x, dec_xb);
  tcast(qkv_m, Wqkv, kE, kD, 3 * kH);
  tcast(wo_m, Wo, kHD, kE, 1);
  gemmb(dec_xb, Wqkv, bqkv_m, qkvb, kBS, 3 * kHD, kE, 2);
  vtrans(qkvb + 2 * kHD, 3 * kHD);
  attn(qkvb, 3 * kHD, qkvb + kHD, 3 * kHD, 1);
  gemmb(ao16, Wo, bo_m, t1, kBS, kE, kHD, 0);
  ln(dec_x, t1, 2, n1, n1b);   // n1d

  tcast(qkv_c, Wqkv, kE, kD, 3 * kH);
  tcast(wo_c, Wo, kHD, kE, 1);
  gemmb(n1b, Wqkv, bqkv_c, qb1, kBS, kHD, kE, 2);
  gemmb(n_encb, Wqkv + (size_t)kHD * kE, bqkv_c + kHD, kvb, kBS, 2 * kHD, kE, 2);
  vtrans(kvb + kHD, 2 * kHD);
  attn(qb1, kHD, kvb, 2 * kHD, 0);
  gemmb(ao16, Wo, bo_c, t1, kBS, kE, kHD, 0);
  ln(n1, t1, 3, enc_x, enc_xb);  // n2d

  tcast(ffw1 + (size_t)kE * kFH, Wf1, kE, kFH, 1);
  tcast(ffw2 + (size_t)kFH * kE, Wf2, kFH, kE, 1);
  gemmb(enc_xb, Wf1, ffb1 + kFH, ffhb, kBS, kFH, kE, 3);
  gemmb(ffhb, Wf2, ffb2 + kE, t1, kBS, kE, kFH, 0);
  ln(enc_x, t1, 4, dec_x, dec_xb);  // n3d

  // ---------------- logits (128x256 pipelined GEMM, 2 blocks/CU) + softmax ----------
  tcast(wout, Wv, kE, kV, 1);
  gemm256_k<<<dim3((kBS / 128) * (kV / 256)), 512, 0, stream>>>(
      dec_xb, Wv, bout, out, kV, kE, kBS / 128);
  softmax_rows_k<<<kBS, 512, 0, stream>>>(out);
}

// Round 8
// 699.551 us; speedup vs baseline: 1.0091x; 1.0091x over previous
//
#include <hip/hip_runtime.h>
#include <hip/hip_bf16.h>
#include <math.h>

namespace {

constexpr int kB = 2, kS = 1024, kE = 1024, kH = 16, kD = 64, kV = 32000, kFH = 512;
constexpr int kBS = kB * kS;   // 2048 rows
constexpr int kHD = kH * kD;   // 1024

typedef __attribute__((ext_vector_type(8))) short bf16x8;
typedef __attribute__((ext_vector_type(4))) float f32x4;

#define GLDS(g, l) __builtin_amdgcn_global_load_lds(                          \
      (const __attribute__((address_space(1))) void*)(g),                     \
      (__attribute__((address_space(3))) void*)(l), 16, 0, 0)

// ---------------- positional-encoding table: pe[s][e], s<kS ----------------
__global__ __launch_bounds__(256) void pe_table_k(float* __restrict__ pe) {
  int s = blockIdx.x;
  float* dst = pe + (size_t)s * kE;
  for (int e = threadIdx.x; e < kE; e += 256) {
    int i = e >> 1;
    float denom = powf(10000.0f, (float)(2 * i) * (1.0f / (float)kE));
    float ang = (float)s / denom;
    dst[e] = (e & 1) ? cosf(ang) : sinf(ang);
  }
}

// ---------------- embedding + PE (dual fp32/bf16 out) ----------------
__global__ __launch_bounds__(256) void embed_pe_k(const int* __restrict__ tok,
                                                  const float* __restrict__ emb,
                                                  const float* __restrict__ pe,
                                                  float* __restrict__ out,
                                                  __hip_bfloat16* __restrict__ outb) {
  int row = blockIdx.x;              // b*S + s
  int s = row & (kS - 1);
  int t = tok[row];
  const float4* src = (const float4*)(emb + (size_t)t * kE);
  const float4* per = (const float4*)(pe + (size_t)s * kE);
  float4* dst = (float4*)(out + (size_t)row * kE);
  __hip_bfloat16* dstb = outb + (size_t)row * kE;
  for (int e4 = threadIdx.x; e4 < kE / 4; e4 += 256) {
    float4 a = src[e4], p = per[e4];
    float4 v = make_float4(a.x + p.x, a.y + p.y, a.z + p.z, a.w + p.w);
    dst[e4] = v;
    union { __hip_bfloat16 h[4]; short4 s4; } u;
    u.h[0] = __float2bfloat16(v.x); u.h[1] = __float2bfloat16(v.y);
    u.h[2] = __float2bfloat16(v.z); u.h[3] = __float2bfloat16(v.w);
    ((short4*)dstb)[e4] = u.s4;
  }
}

// ---------------- transpose + cast: src[R,C] fp32 -> dst[C,R] bf16 (batched) -------
__global__ __launch_bounds__(256) void tcast_k(const float* __restrict__ src,
                                               __hip_bfloat16* __restrict__ dst,
                                               int R, int C) {
  __shared__ float tile[32][33];
  src += (size_t)blockIdx.z * R * C;
  dst += (size_t)blockIdx.z * R * C;
  int c0 = blockIdx.x * 32, r0 = blockIdx.y * 32;
  int tx = threadIdx.x & 31, ty = threadIdx.x >> 5;   // ty in 0..7
#pragma unroll
  for (int i = 0; i < 32; i += 8)
    tile[ty + i][tx] = src[(size_t)(r0 + ty + i) * C + c0 + tx];
  __syncthreads();
#pragma unroll
  for (int i = 0; i < 32; i += 8)
    dst[(size_t)(c0 + ty + i) * R + r0 + tx] = __float2bfloat16(tile[tx][ty + i]);
}

// ---------------- bf16 transpose per head: v[BS, sV] -> vt[(b*H+h)*64 + d][S] ------
__global__ __launch_bounds__(256) void vtrans_k(const __hip_bfloat16* __restrict__ v,
                                                int sV, __hip_bfloat16* __restrict__ vt) {
  __shared__ unsigned short tile[32][34];
  int s0 = blockIdx.x * 32, d0 = blockIdx.y * 32, bh = blockIdx.z;
  int b = bh >> 4, h = bh & 15;
  int tx = threadIdx.x & 31, ty = threadIdx.x >> 5;
  const unsigned short* src = (const unsigned short*)v;
  unsigned short* dst = (unsigned short*)vt;
#pragma unroll
  for (int i = 0; i < 32; i += 8)
    tile[ty + i][tx] = src[(size_t)(b * kS + s0 + ty + i) * sV + h * 64 + d0 + tx];
  __syncthreads();
#pragma unroll
  for (int i = 0; i < 32; i += 8)
    dst[(size_t)(bh * 64 + d0 + ty + i) * kS + s0 + tx] = tile[tx][ty + i];
}

// ---------------- 128x128 bf16 GEMM, 3-buffer BK=32 counted-vmcnt pipeline ---------
// mode: 0 = fp32 out, 1 = fp32+relu, 2 = bf16 out, 3 = bf16+relu
__global__ __launch_bounds__(256) void gemm_bf16_k(
    const __hip_bfloat16* __restrict__ A,   // [M,K] bf16
    const __hip_bfloat16* __restrict__ Bt,  // [N,K] bf16
    const float* __restrict__ bias,         // [N]
    void* __restrict__ Cout,
    int N, int K, int mode, int gridM) {
  __shared__ __align__(16) char L[3][16384];   // per buf: A 8KB | B 8KB
  const int nwg = gridDim.x, id = blockIdx.x;
  const int swz = (id & 7) * (nwg >> 3) + (id >> 3);
  const int bm = (swz % gridM) * 128, bn = (swz / gridM) * 128;
  const int tid = threadIdx.x, w = tid >> 6, lane = tid & 63;
  const int wr = w >> 1, wc = w & 1;
  const int lr = lane & 15, kg = lane >> 4;
  const int NT = K >> 5;
  const __hip_bfloat16* Ag = A + (size_t)bm * K;
  const __hip_bfloat16* Bg = Bt + (size_t)bn * K;

  auto stage = [&](int t) {   // 4 loads/thread (A 2 + B 2)
    const int buf = t % 3, k0 = t * 32;
#pragma unroll
    for (int j = 0; j < 2; ++j) {
      int slot = w * 64 + lane + j * 256;          // 0..511 (16B slots)
      int row = slot >> 2;
      int cs = (slot & 3) ^ ((row >> 1) & 3);      // inverse swizzle on source
      GLDS(Ag + (size_t)row * K + k0 + cs * 8, L[buf] + w * 1024 + j * 4096);
      GLDS(Bg + (size_t)row * K + k0 + cs * 8, L[buf] + 8192 + w * 1024 + j * 4096);
    }
  };

  f32x4 acc[4][4] = {};
  stage(0);
  stage(1);
  asm volatile("s_waitcnt vmcnt(4)" ::: "memory");
  __builtin_amdgcn_s_barrier();

  for (int t = 0; t < NT; ++t) {
    const char* buf = L[t % 3];
    if (t + 2 < NT) stage(t + 2);
    bf16x8 af[4], bfr[4];
#pragma unroll
    for (int i = 0; i < 4; ++i) {
      int row = wr * 64 + i * 16 + lr;
      af[i] = *(const bf16x8*)(buf + row * 64 + ((kg ^ ((row >> 1) & 3)) << 4));
    }
#pragma unroll
    for (int j = 0; j < 4; ++j) {
      int row = wc * 64 + j * 16 + lr;
      bfr[j] = *(const bf16x8*)(buf + 8192 + row * 64 + ((kg ^ ((row >> 1) & 3)) << 4));
    }
    __builtin_amdgcn_s_setprio(1);
#pragma unroll
    for (int i = 0; i < 4; ++i)
#pragma unroll
      for (int j = 0; j < 4; ++j)
        acc[i][j] = __builtin_amdgcn_mfma_f32_16x16x32_bf16(af[i], bfr[j], acc[i][j], 0, 0, 0);
    __builtin_amdgcn_s_setprio(0);
    if (t + 2 < NT)
      asm volatile("s_waitcnt vmcnt(4) lgkmcnt(0)" ::: "memory");
    else
      asm volatile("s_waitcnt vmcnt(0) lgkmcnt(0)" ::: "memory");
    __builtin_amdgcn_s_barrier();
  }

  float* Cf = (float*)Cout;
  __hip_bfloat16* Cb = (__hip_bfloat16*)Cout;
#pragma unroll
  for (int j = 0; j < 4; ++j) {
    int col = bn + wc * 64 + j * 16 + lr;
    float bc = bias[col];
#pragma unroll
    for (int i = 0; i < 4; ++i) {
      int rbase = bm + wr * 64 + i * 16 + kg * 4;
#pragma unroll
      for (int r = 0; r < 4; ++r) {
        float val = acc[i][j][r] + bc;
        if (mode & 1) val = fmaxf(val, 0.0f);
        if (mode < 2) Cf[(size_t)(rbase + r) * N + col] = val;
        else          Cb[(size_t)(rbase + r) * N + col] = __float2bfloat16(val);
      }
    }
  }
}

// ---------------- 256x256 bf16 GEMM, m201-style phase pipeline (vocab) ------------
// 8 waves (2M x 4N), wave tile 128x64. BK=32, 3 buffers (96 KB), prefetch dist 2.
// Per K-tile: 2 phases x 16 MFMA, each phase = {ds_read subtile, stage half(t+2),
// barrier, lgkmcnt(0), setprio, MFMA, setprio, barrier}; vmcnt(4) once per tile.
__global__ __launch_bounds__(512, 2) void gemm256_k(
    const __hip_bfloat16* __restrict__ A,   // [M,K]
    const __hip_bfloat16* __restrict__ Bt,  // [N,K]
    const float* __restrict__ bias,
    float* __restrict__ C,
    int N, int K, int gridM) {
  __shared__ __align__(16) char L[3][32768];   // per buf: A 16KB | B 16KB
  const int tid = threadIdx.x, w = tid >> 6, lane = tid & 63;
  const int wm = w >> 2, wn = w & 3;           // wave tile 128x64
  const int lr = lane & 15, kg = lane >> 4;
  const int nwg = gridDim.x, id = blockIdx.x;
  const int swz = (id & 7) * (nwg >> 3) + (id >> 3);
  const int bm = (swz % gridM) * 256, bn = (swz / gridM) * 256;
  const int NT = K >> 5;
  const __hip_bfloat16* Ag = A + (size_t)bm * K;
  const __hip_bfloat16* Bg = Bt + (size_t)bn * K;

  auto stageA = [&](int t) {   // 2 loads/thread -> 16 KB A half
    const int buf = t % 3, k0 = t * 32;
#pragma unroll
    for (int j = 0; j < 2; ++j) {
      int slot = tid + j * 512;                    // 0..1023
      int row = slot >> 2;                         // 0..255
      int cs = (slot & 3) ^ ((row >> 1) & 3);
      GLDS(Ag + (size_t)row * K + k0 + cs * 8, L[buf] + slot * 16);
    }
  };
  auto stageB = [&](int t) {
    const int buf = t % 3, k0 = t * 32;
#pragma unroll
    for (int j = 0; j < 2; ++j) {
      int slot = tid + j * 512;
      int row = slot >> 2;
      int cs = (slot & 3) ^ ((row >> 1) & 3);
      GLDS(Bg + (size_t)row * K + k0 + cs * 8, L[buf] + 16384 + slot * 16);
    }
  };

  f32x4 acc[8][4] = {};
  stageA(0); stageB(0);
  stageA(1); stageB(1);
  asm volatile("s_waitcnt vmcnt(4)" ::: "memory");
  __builtin_amdgcn_s_barrier();

  for (int t = 0; t < NT; ++t) {
    const char* buf = L[t % 3];
    bf16x8 aA[4], aB[4];
    // ---------------- phase 0: quadrant rows [0,64) of wave tile ----------------
#pragma unroll
    for (int i = 0; i < 4; ++i) {
      int row = wm * 128 + i * 16 + lr;
      aA[i] = *(const bf16x8*)(buf + row * 64 + ((kg ^ ((row >> 1) & 3)) << 4));
    }
#pragma unroll
    for (int n = 0; n < 4; ++n) {
      int row = wn * 64 + n * 16 + lr;
      aB[n] = *(const bf16x8*)(buf + 16384 + row * 64 + ((kg ^ ((row >> 1) & 3)) << 4));
    }
    if (t + 2 < NT) stageA(t + 2);
    __builtin_amdgcn_s_barrier();
    asm volatile("s_waitcnt lgkmcnt(0)" ::: "memory");
    __builtin_amdgcn_sched_barrier(0);
    __builtin_amdgcn_s_setprio(1);
#pragma unroll
    for (int i = 0; i < 4; ++i)
#pragma unroll
      for (int n = 0; n < 4; ++n)
        acc[i][n] = __builtin_amdgcn_mfma_f32_16x16x32_bf16(aA[i], aB[n], acc[i][n], 0, 0, 0);
    __builtin_amdgcn_s_setprio(0);
    __builtin_amdgcn_sched_barrier(0);
    __builtin_amdgcn_s_barrier();
    // ---------------- phase 1: quadrant rows [64,128) (B reused in regs) --------
#pragma unroll
    for (int i = 0; i < 4; ++i) {
      int row = wm * 128 + 64 + i * 16 + lr;
      aA[i] = *(const bf16x8*)(buf + row * 64 + ((kg ^ ((row >> 1) & 3)) << 4));
    }
    if (t + 2 < NT) stageB(t + 2);
    __builtin_amdgcn_s_barrier();
    asm volatile("s_waitcnt lgkmcnt(0)" ::: "memory");
    __builtin_amdgcn_sched_barrier(0);
    __builtin_amdgcn_s_setprio(1);
#pragma unroll
    for (int i = 0; i < 4; ++i)
#pragma unroll
      for (int n = 0; n < 4; ++n)
        acc[4 + i][n] = __builtin_amdgcn_mfma_f32_16x16x32_bf16(aA[i], aB[n], acc[4 + i][n], 0, 0, 0);
    __builtin_amdgcn_s_setprio(0);
    __builtin_amdgcn_sched_barrier(0);
    // ---- tile publish: tile t+1 must be landed; t+2's 4 loads stay in flight ----
    if (t + 2 < NT)
      asm volatile("s_waitcnt vmcnt(4)" ::: "memory");
    else if (t + 1 < NT)
      asm volatile("s_waitcnt vmcnt(0)" ::: "memory");
    __builtin_amdgcn_s_barrier();
  }

  // epilogue
#pragma unroll
  for (int mg = 0; mg < 8; ++mg) {
    int rbase = bm + wm * 128 + mg * 16 + (kg << 2);
#pragma unroll
    for (int n = 0; n < 4; ++n) {
      int col = bn + (wn << 6) + n * 16 + lr;
      float bc = bias[col];
#pragma unroll
      for (int r = 0; r < 4; ++r)
        C[(size_t)(rbase + r) * N + col] = acc[mg][n][r] + bc;
    }
  }
}

// ---------------- MFMA flash attention ----------------
__global__ __launch_bounds__(256) void attn_mfma_k(
    const __hip_bfloat16* __restrict__ q, int sQ,
    const __hip_bfloat16* __restrict__ k, int sK,
    const __hip_bfloat16* __restrict__ vt,   // [(b*H+h)*64 + d][S]
    __hip_bfloat16* __restrict__ o,          // [BS][HD]
    int causal) {
  __shared__ __align__(16) char Ks[8192];
  __shared__ __align__(16) char Vs[8192];
  __shared__ __align__(16) char Ps[4][2304];   // per-wave P tile [16 q][72 bf16]
  const int tid = threadIdx.x, w = tid >> 6, l = tid & 63;
  const int lr = l & 15, lg = l >> 4;
  const int q0 = blockIdx.x * 64, h = blockIdx.y, b = blockIdx.z;

  const int qrow = q0 + w * 16 + lr;
  const __hip_bfloat16* qp = q + (size_t)(b * kS + qrow) * sQ + h * 64 + lg * 8;
  bf16x8 aQ0 = *(const bf16x8*)qp;
  bf16x8 aQ1 = *(const bf16x8*)(qp + 32);

  f32x4 oacc[4] = {};
  float mrun[4], lrun[4];
#pragma unroll
  for (int r = 0; r < 4; ++r) { mrun[r] = -INFINITY; lrun[r] = 0.0f; }

  const int ntiles = causal ? ((q0 >> 6) + 1) : (kS >> 6);
  const int diagT = causal ? (q0 >> 6) : -1;
  const char* kbase = (const char*)(k + (size_t)(b * kS) * sK + h * 64);
  const char* vbase = (const char*)(vt + (size_t)((b * kH + h) * 64) * kS);
  char* Pw = Ps[w];

  for (int t = 0; t < ntiles; ++t) {
    const int kv0 = t * 64;
    __syncthreads();
#pragma unroll
    for (int i = 0; i < 2; ++i) {
      int slot = w * 128 + i * 64 + l;
      int row = slot >> 3, sl = slot & 7, c = sl ^ (row & 7);
      const char* gk = kbase + (size_t)(kv0 + row) * sK * 2 + c * 16;
      const char* gv = vbase + (size_t)row * kS * 2 + kv0 * 2 + c * 16;
      GLDS(gk, Ks + (w * 128 + i * 64) * 16);
      GLDS(gv, Vs + (w * 128 + i * 64) * 16);
    }
    __syncthreads();

    // ---- S = Q @ K^T ----
    f32x4 sacc[4] = {};
#pragma unroll
    for (int nf = 0; nf < 4; ++nf) {
      int key = nf * 16 + lr;
#pragma unroll
      for (int kf = 0; kf < 2; ++kf) {
        int ch = (lg + kf * 4) ^ (key & 7);
        bf16x8 bK = *(const bf16x8*)(Ks + key * 128 + ch * 16);
        sacc[nf] = __builtin_amdgcn_mfma_f32_16x16x32_bf16(kf ? aQ1 : aQ0, bK, sacc[nf], 0, 0, 0);
      }
    }

    // ---- online softmax ----
#pragma unroll
    for (int r = 0; r < 4; ++r) {
      int row16 = lg * 4 + r;
      int qg = q0 + w * 16 + row16;
      float sv[4];
#pragma unroll
      for (int nf = 0; nf < 4; ++nf) {
        float s = sacc[nf][r] * 0.125f;
        if (t == diagT && (kv0 + nf * 16 + lr) > qg) s = -INFINITY;
        sv[nf] = s;
      }
      float mx = fmaxf(fmaxf(sv[0], sv[1]), fmaxf(sv[2], sv[3]));
#pragma unroll
      for (int m = 1; m < 16; m <<= 1) mx = fmaxf(mx, __shfl_xor(mx, m));
      float mnew = fmaxf(mrun[r], mx);
      float sc = __expf(mrun[r] - mnew);
      mrun[r] = mnew;
      float rs = 0.0f;
#pragma unroll
      for (int nf = 0; nf < 4; ++nf) {
        float p = __expf(sv[nf] - mnew);
        rs += p;
        *(__hip_bfloat16*)(Pw + row16 * 144 + (nf * 16 + lr) * 2) = __float2bfloat16(p);
      }
#pragma unroll
      for (int m = 1; m < 16; m <<= 1) rs += __shfl_xor(rs, m);
      lrun[r] = lrun[r] * sc + rs;
#pragma unroll
      for (int nfd = 0; nfd < 4; ++nfd) oacc[nfd][r] *= sc;
    }

    // ---- O += P @ V ----
    bf16x8 aP0 = *(const bf16x8*)(Pw + lr * 144 + (lg * 8) * 2);
    bf16x8 aP1 = *(const bf16x8*)(Pw + lr * 144 + (lg * 8 + 32) * 2);
#pragma unroll
    for (int nfd = 0; nfd < 4; ++nfd) {
      int d = nfd * 16 + lr;
#pragma unroll
      for (int kf = 0; kf < 2; ++kf) {
        int ch = (lg + kf * 4) ^ (d & 7);
        bf16x8 bV = *(const bf16x8*)(Vs + d * 128 + ch * 16);
        oacc[nfd] = __builtin_amdgcn_mfma_f32_16x16x32_bf16(kf ? aP1 : aP0, bV, oacc[nfd], 0, 0, 0);
      }
    }
  }

#pragma unroll
  for (int r = 0; r < 4; ++r) {
    float inv = 1.0f / lrun[r];
    int rowg = q0 + w * 16 + lg * 4 + r;
#pragma unroll
    for (int nfd = 0; nfd < 4; ++nfd)
      o[(size_t)(b * kS + rowg) * kHD + h * 64 + nfd * 16 + lr] =
          __float2bfloat16(oacc[nfd][r] * inv);
  }
}

// ---------------- residual + LayerNorm (dual fp32/bf16 out, float4) ----------------
__global__ __launch_bounds__(256) void ln_res_k(const float* __restrict__ a,
                                                const float* __restrict__ b,
                                                const float* __restrict__ gamma,
                                                const float* __restrict__ beta,
                                                float* __restrict__ out,
                                                __hip_bfloat16* __restrict__ outb) {
  __shared__ float sh[10];
  int row = blockIdx.x, tid = threadIdx.x;
  const float4* a4 = (const float4*)(a + (size_t)row * kE);
  const float4* b4 = (const float4*)(b + (size_t)row * kE);
  float4 t = a4[tid], u = b4[tid];
  t.x += u.x; t.y += u.y; t.z += u.z; t.w += u.w;
  float s = t.x + t.y + t.z + t.w;
  float q2 = t.x * t.x + t.y * t.y + t.z * t.z + t.w * t.w;
  for (int o = 32; o > 0; o >>= 1) { s += __shfl_down(s, o); q2 += __shfl_down(q2, o); }
  int lane = tid & 63, wid = tid >> 6;
  if (lane == 0) { sh[wid] = s; sh[4 + wid] = q2; }
  __syncthreads();
  if (tid == 0) {
    float S2 = sh[0] + sh[1] + sh[2] + sh[3];
    float Q2 = sh[4] + sh[5] + sh[6] + sh[7];
    float mean = S2 * (1.0f / kE);
    float var = Q2 * (1.0f / kE) - mean * mean;
    sh[8] = mean;
    sh[9] = rsqrtf(var + 1e-15f);
  }
  __syncthreads();
  float mean = sh[8], inv = sh[9];
  float4 g = ((const float4*)gamma)[tid], be = ((const float4*)beta)[tid];
  float4 v;
  v.x = g.x * ((t.x - mean) * inv) + be.x;
  v.y = g.y * ((t.y - mean) * inv) + be.y;
  v.z = g.z * ((t.z - mean) * inv) + be.z;
  v.w = g.w * ((t.w - mean) * inv) + be.w;
  ((float4*)(out + (size_t)row * kE))[tid] = v;
  union { __hip_bfloat16 h[4]; short4 s4; } uo;
  uo.h[0] = __float2bfloat16(v.x); uo.h[1] = __float2bfloat16(v.y);
  uo.h[2] = __float2bfloat16(v.z); uo.h[3] = __float2bfloat16(v.w);
  ((short4*)(outb + (size_t)row * kE))[tid] = uo.s4;
}

// ---------------- row softmax over V (in place, register-resident single pass) -----
__global__ __launch_bounds__(512) void softmax_rows_k(float* __restrict__ x) {
  __shared__ float sh[18];
  int row = blockIdx.x;
  float4* x4 = (float4*)(x + (size_t)row * kV);
  const int n4 = kV / 4;   // 8000
  int tid = threadIdx.x;
  float4 v[16];
  float m = -INFINITY, sum = 0.0f;
#pragma unroll
  for (int i = 0; i < 16; ++i) {
    int idx = tid + i * 512;
    if (idx < n4) {
      v[i] = x4[idx];
      float mx = fmaxf(fmaxf(v[i].x, v[i].y), fmaxf(v[i].z, v[i].w));
      float nm = fmaxf(m, mx);
      sum = sum * __expf(m - nm) + __expf(v[i].x - nm) + __expf(v[i].y - nm) +
            __expf(v[i].z - nm) + __expf(v[i].w - nm);
      m = nm;
    }
  }
  for (int o = 32; o > 0; o >>= 1) {
    float om = __shfl_down(m, o), os = __shfl_down(sum, o);
    float nm = fmaxf(m, om);
    sum = sum * __expf(m - nm) + os * __expf(om - nm);
    m = nm;
  }
  int lane = tid & 63, wid = tid >> 6;
  if (lane == 0) { sh[wid] = m; sh[8 + wid] = sum; }
  __syncthreads();
  if (tid == 0) {
    float M = sh[0], S2 = 0.0f;
#pragma unroll
    for (int i2 = 1; i2 < 8; ++i2) M = fmaxf(M, sh[i2]);
#pragma unroll
    for (int i2 = 0; i2 < 8; ++i2) S2 += sh[8 + i2] * __expf(sh[i2] - M);
    sh[16] = M;
    sh[17] = 1.0f / S2;
  }
  __syncthreads();
  float M = sh[16], rcp = sh[17];
#pragma unroll
  for (int i = 0; i < 16; ++i) {
    int idx = tid + i * 512;
    if (idx < n4) {
      float4 o2;
      o2.x = __expf(v[i].x - M) * rcp;
      o2.y = __expf(v[i].y - M) * rcp;
      o2.z = __expf(v[i].z - M) * rcp;
      o2.w = __expf(v[i].w - M) * rcp;
      x4[idx] = o2;
    }
  }
}

}  // namespace

extern "C" void kernel_launch(void* const* d_in, const int* in_sizes, int n_in,
                              void* d_out, int out_size, void* d_ws, size_t ws_size,
                              hipStream_t stream) {
  const int*   src    = (const int*)d_in[0];
  const int*   trg    = (const int*)d_in[1];
  const float* emb_e  = (const float*)d_in[2];
  const float* emb_d  = (const float*)d_in[3];
  const float* qkv_e  = (const float*)d_in[4];
  const float* bqkv_e = (const float*)d_in[5];
  const float* wo_e   = (const float*)d_in[6];
  const float* bo_e   = (const float*)d_in[7];
  const float* qkv_m  = (const float*)d_in[8];
  const float* bqkv_m = (const float*)d_in[9];
  const float* wo_m   = (const float*)d_in[10];
  const float* bo_m   = (const float*)d_in[11];
  const float* qkv_c  = (const float*)d_in[12];
  const float* bqkv_c = (const float*)d_in[13];
  const float* wo_c   = (const float*)d_in[14];
  const float* bo_c   = (const float*)d_in[15];
  const float* gamma  = (const float*)d_in[16];
  const float* beta   = (const float*)d_in[17];
  const float* ffw1   = (const float*)d_in[18];
  const float* ffb1   = (const float*)d_in[19];
  const float* ffw2   = (const float*)d_in[20];
  const float* ffb2   = (const float*)d_in[21];
  const float* wout   = (const float*)d_in[22];
  const float* bout   = (const float*)d_in[23];
  float* out = (float*)d_out;

  float* w = (float*)d_ws;
  const size_t R = (size_t)kBS * kE;   // 2M elements
  float* enc_x = w + 0 * R;            // reused as n2d
  float* dec_x = w + 1 * R;            // reused as n3d
  float* t1    = w + 2 * R;
  float* n1    = w + 3 * R;            // reused as n1d
  float* n_enc = w + 4 * R;
  __hip_bfloat16* bb     = (__hip_bfloat16*)(w + 5 * R);
  __hip_bfloat16* enc_xb = bb;                       // R
  __hip_bfloat16* dec_xb = enc_xb + R;               // R
  __hip_bfloat16* n1b    = dec_xb + R;               // R
  __hip_bfloat16* n_encb = n1b + R;                  // R
  __hip_bfloat16* qkvb   = n_encb + R;               // 3R   [BS, 3HD]
  __hip_bfloat16* kvb    = qkvb + 3 * R;             // 2R   [BS, 2HD]
  __hip_bfloat16* qb1    = kvb + 2 * R;              // R    [BS, HD]
  __hip_bfloat16* vtb    = qb1 + R;                  // R    [B*H*64, S]
  __hip_bfloat16* ao16   = vtb + R;                  // R
  __hip_bfloat16* ffhb   = ao16 + R;                 // R/2
  __hip_bfloat16* Wqkv   = ffhb + R / 2;             // 1.5R  [3HD, E]
  __hip_bfloat16* Wo     = Wqkv + (size_t)3 * kHD * kE;
  __hip_bfloat16* Wf1 = Wo + (size_t)kE * kHD;       // [FH, E]
  __hip_bfloat16* Wf2 = Wf1 + (size_t)kFH * kE;      // [E, FH]
  __hip_bfloat16* Wv  = Wf2 + (size_t)kE * kFH;      // [V, E]
  float* pe = (float*)Wv;   // alias: PE table used before Wv is written

  auto tcast = [&](const float* s, __hip_bfloat16* d, int Rr, int Cc, int batch) {
    tcast_k<<<dim3(Cc / 32, Rr / 32, batch), 256, 0, stream>>>(s, d, Rr, Cc);
  };
  auto gemmb = [&](const __hip_bfloat16* A, const __hip_bfloat16* Bt, const float* bias,
                   void* C, int M, int N, int K, int mode) {
    int gridM = M / 128;
    gemm_bf16_k<<<dim3(gridM * (N / 128)), 256, 0, stream>>>(A, Bt, bias, C, N, K, mode, gridM);
  };
  auto vtrans = [&](const __hip_bfloat16* v, int sV) {
    vtrans_k<<<dim3(kS / 32, kD / 32, kB * kH), 256, 0, stream>>>(v, sV, vtb);
  };
  auto attn = [&](const __hip_bfloat16* q, int sQ, const __hip_bfloat16* k, int sK,
                  int causal) {
    attn_mfma_k<<<dim3(kS / 64, kH, kB), 256, 0, stream>>>(q, sQ, k, sK, vtb, ao16, causal);
  };
  auto ln = [&](const float* a, const float* b2, int sel, float* o1, __hip_bfloat16* o2) {
    ln_res_k<<<kBS, 256, 0, stream>>>(a, b2, gamma + sel * kE, beta + sel * kE, o1, o2);
  };

  pe_table_k<<<kS, 256, 0, stream>>>(pe);

  // ---------------- encoder ----------------
  embed_pe_k<<<kBS, 256, 0, stream>>>(src, emb_e, pe, enc_x, enc_xb);
  tcast(qkv_e, Wqkv, kE, kD, 3 * kH);
  tcast(wo_e, Wo, kHD, kE, 1);
  gemmb(enc_xb, Wqkv, bqkv_e, qkvb, kBS, 3 * kHD, kE, 2);
  vtrans(qkvb + 2 * kHD, 3 * kHD);
  attn(qkvb, 3 * kHD, qkvb + kHD, 3 * kHD, 0);
  gemmb(ao16, Wo, bo_e, t1, kBS, kE, kHD, 0);
  ln(enc_x, t1, 0, n1, n1b);
  tcast(ffw1, Wf1, kE, kFH, 1);
  tcast(ffw2, Wf2, kFH, kE, 1);
  gemmb(n1b, Wf1, ffb1, ffhb, kBS, kFH, kE, 3);
  gemmb(ffhb, Wf2, ffb2, t1, kBS, kE, kFH, 0);
  ln(n1, t1, 1, n_enc, n_encb);

  // ---------------- decoder ----------------
  embed_pe_k<<<kBS, 256, 0, stream>>>(trg, emb_d, pe, dec_x, dec_xb);
  tcast(qkv_m, Wqkv, kE, kD, 3 * kH);
  tcast(wo_m, Wo, kHD, kE, 1);
  gemmb(dec_xb, Wqkv, bqkv_m, qkvb, kBS, 3 * kHD, kE, 2);
  vtrans(qkvb + 2 * kHD, 3 * kHD);
  attn(qkvb, 3 * kHD, qkvb + kHD, 3 * kHD, 1);
  gemmb(ao16, Wo, bo_m, t1, kBS, kE, kHD, 0);
  ln(dec_x, t1, 2, n1, n1b);   // n1d

  tcast(qkv_c, Wqkv, kE, kD, 3 * kH);
  tcast(wo_c, Wo, kHD, kE, 1);
  gemmb(n1b, Wqkv, bqkv_c, qb1, kBS, kHD, kE, 2);
  gemmb(n_encb, Wqkv + (size_t)kHD * kE, bqkv_c + kHD, kvb, kBS, 2 * kHD, kE, 2);
  vtrans(kvb + kHD, 2 * kHD);
  attn(qb1, kHD, kvb, 2 * kHD, 0);
  gemmb(ao16, Wo, bo_c, t1, kBS, kE, kHD, 0);
  ln(n1, t1, 3, enc_x, enc_xb);  // n2d

  tcast(ffw1 + (size_t)kE * kFH, Wf1, kE, kFH, 1);
  tcast(ffw2 + (size_t)kFH * kE, Wf2, kFH, kE, 1);
  gemmb(enc_xb, Wf1, ffb1 + kFH, ffhb, kBS, kFH, kE, 3);
  gemmb(ffhb, Wf2, ffb2 + kE, t1, kBS, kE, kFH, 0);
  ln(enc_x, t1, 4, dec_x, dec_xb);  // n3d

  // ---------------- logits (256^2 phase-pipelined GEMM) + softmax ----------------
  tcast(wout, Wv, kE, kV, 1);
  gemm256_k<<<dim3((kBS / 256) * (kV / 256)), 512, 0, stream>>>(
      dec_xb, Wv, bout, out, kV, kE, kBS / 256);
  softmax_rows_k<<<kBS, 512, 0, stream>>>(out);
}

// Round 9
// 666.617 us; speedup vs baseline: 1.0590x; 1.0494x over previous
//
#include <hip/hip_runtime.h>
#include <hip/hip_bf16.h>
#include <hip/hip_fp16.h>
#include <math.h>

namespace {

constexpr int kB = 2, kS = 1024, kE = 1024, kH = 16, kD = 64, kV = 32000, kFH = 512;
constexpr int kBS = kB * kS;   // 2048 rows
constexpr int kHD = kH * kD;   // 1024

typedef __attribute__((ext_vector_type(8))) short bf16x8;
typedef __attribute__((ext_vector_type(8))) unsigned short u16x8;
typedef __attribute__((ext_vector_type(4))) float f32x4;

#define GLDS(g, l) __builtin_amdgcn_global_load_lds(                          \
      (const __attribute__((address_space(1))) void*)(g),                     \
      (__attribute__((address_space(3))) void*)(l), 16, 0, 0)

// ---------------- positional-encoding table: pe[s][e], s<kS ----------------
__global__ __launch_bounds__(256) void pe_table_k(float* __restrict__ pe) {
  int s = blockIdx.x;
  float* dst = pe + (size_t)s * kE;
  for (int e = threadIdx.x; e < kE; e += 256) {
    int i = e >> 1;
    float denom = powf(10000.0f, (float)(2 * i) * (1.0f / (float)kE));
    float ang = (float)s / denom;
    dst[e] = (e & 1) ? cosf(ang) : sinf(ang);
  }
}

// ---------------- embedding + PE (dual fp32/bf16 out) ----------------
__global__ __launch_bounds__(256) void embed_pe_k(const int* __restrict__ tok,
                                                  const float* __restrict__ emb,
                                                  const float* __restrict__ pe,
                                                  float* __restrict__ out,
                                                  __hip_bfloat16* __restrict__ outb) {
  int row = blockIdx.x;              // b*S + s
  int s = row & (kS - 1);
  int t = tok[row];
  const float4* src = (const float4*)(emb + (size_t)t * kE);
  const float4* per = (const float4*)(pe + (size_t)s * kE);
  float4* dst = (float4*)(out + (size_t)row * kE);
  __hip_bfloat16* dstb = outb + (size_t)row * kE;
  for (int e4 = threadIdx.x; e4 < kE / 4; e4 += 256) {
    float4 a = src[e4], p = per[e4];
    float4 v = make_float4(a.x + p.x, a.y + p.y, a.z + p.z, a.w + p.w);
    dst[e4] = v;
    union { __hip_bfloat16 h[4]; short4 s4; } u;
    u.h[0] = __float2bfloat16(v.x); u.h[1] = __float2bfloat16(v.y);
    u.h[2] = __float2bfloat16(v.z); u.h[3] = __float2bfloat16(v.w);
    ((short4*)dstb)[e4] = u.s4;
  }
}

// ---------------- transpose + cast: src[R,C] fp32 -> dst[C,R] bf16 (batched) -------
__global__ __launch_bounds__(256) void tcast_k(const float* __restrict__ src,
                                               __hip_bfloat16* __restrict__ dst,
                                               int R, int C) {
  __shared__ float tile[32][33];
  src += (size_t)blockIdx.z * R * C;
  dst += (size_t)blockIdx.z * R * C;
  int c0 = blockIdx.x * 32, r0 = blockIdx.y * 32;
  int tx = threadIdx.x & 31, ty = threadIdx.x >> 5;   // ty in 0..7
#pragma unroll
  for (int i = 0; i < 32; i += 8)
    tile[ty + i][tx] = src[(size_t)(r0 + ty + i) * C + c0 + tx];
  __syncthreads();
#pragma unroll
  for (int i = 0; i < 32; i += 8)
    dst[(size_t)(c0 + ty + i) * R + r0 + tx] = __float2bfloat16(tile[tx][ty + i]);
}

// ---------------- bf16 transpose per head: v[BS, sV] -> vt[(b*H+h)*64 + d][S] ------
__global__ __launch_bounds__(256) void vtrans_k(const __hip_bfloat16* __restrict__ v,
                                                int sV, __hip_bfloat16* __restrict__ vt) {
  __shared__ unsigned short tile[32][34];
  int s0 = blockIdx.x * 32, d0 = blockIdx.y * 32, bh = blockIdx.z;
  int b = bh >> 4, h = bh & 15;
  int tx = threadIdx.x & 31, ty = threadIdx.x >> 5;
  const unsigned short* src = (const unsigned short*)v;
  unsigned short* dst = (unsigned short*)vt;
#pragma unroll
  for (int i = 0; i < 32; i += 8)
    tile[ty + i][tx] = src[(size_t)(b * kS + s0 + ty + i) * sV + h * 64 + d0 + tx];
  __syncthreads();
#pragma unroll
  for (int i = 0; i < 32; i += 8)
    dst[(size_t)(bh * 64 + d0 + ty + i) * kS + s0 + tx] = tile[tx][ty + i];
}

// ---------------- 128x128 bf16 GEMM, 3-buffer BK=32 counted-vmcnt pipeline ---------
// mode: 0 = fp32 out, 1 = fp32+relu, 2 = bf16 out, 3 = bf16+relu
__global__ __launch_bounds__(256) void gemm_bf16_k(
    const __hip_bfloat16* __restrict__ A,   // [M,K] bf16
    const __hip_bfloat16* __restrict__ Bt,  // [N,K] bf16
    const float* __restrict__ bias,         // [N]
    void* __restrict__ Cout,
    int N, int K, int mode, int gridM) {
  __shared__ __align__(16) char L[3][16384];   // per buf: A 8KB | B 8KB
  const int nwg = gridDim.x, id = blockIdx.x;
  const int swz = (id & 7) * (nwg >> 3) + (id >> 3);
  const int bm = (swz % gridM) * 128, bn = (swz / gridM) * 128;
  const int tid = threadIdx.x, w = tid >> 6, lane = tid & 63;
  const int wr = w >> 1, wc = w & 1;
  const int lr = lane & 15, kg = lane >> 4;
  const int NT = K >> 5;
  const __hip_bfloat16* Ag = A + (size_t)bm * K;
  const __hip_bfloat16* Bg = Bt + (size_t)bn * K;

  auto stage = [&](int t) {   // 4 loads/thread (A 2 + B 2)
    const int buf = t % 3, k0 = t * 32;
#pragma unroll
    for (int j = 0; j < 2; ++j) {
      int slot = w * 64 + lane + j * 256;          // 0..511 (16B slots)
      int row = slot >> 2;
      int cs = (slot & 3) ^ ((row >> 1) & 3);      // inverse swizzle on source
      GLDS(Ag + (size_t)row * K + k0 + cs * 8, L[buf] + w * 1024 + j * 4096);
      GLDS(Bg + (size_t)row * K + k0 + cs * 8, L[buf] + 8192 + w * 1024 + j * 4096);
    }
  };

  f32x4 acc[4][4] = {};
  stage(0);
  stage(1);
  asm volatile("s_waitcnt vmcnt(4)" ::: "memory");
  __builtin_amdgcn_s_barrier();

  for (int t = 0; t < NT; ++t) {
    const char* buf = L[t % 3];
    if (t + 2 < NT) stage(t + 2);
    bf16x8 af[4], bfr[4];
#pragma unroll
    for (int i = 0; i < 4; ++i) {
      int row = wr * 64 + i * 16 + lr;
      af[i] = *(const bf16x8*)(buf + row * 64 + ((kg ^ ((row >> 1) & 3)) << 4));
    }
#pragma unroll
    for (int j = 0; j < 4; ++j) {
      int row = wc * 64 + j * 16 + lr;
      bfr[j] = *(const bf16x8*)(buf + 8192 + row * 64 + ((kg ^ ((row >> 1) & 3)) << 4));
    }
    __builtin_amdgcn_s_setprio(1);
#pragma unroll
    for (int i = 0; i < 4; ++i)
#pragma unroll
      for (int j = 0; j < 4; ++j)
        acc[i][j] = __builtin_amdgcn_mfma_f32_16x16x32_bf16(af[i], bfr[j], acc[i][j], 0, 0, 0);
    __builtin_amdgcn_s_setprio(0);
    if (t + 2 < NT)
      asm volatile("s_waitcnt vmcnt(4) lgkmcnt(0)" ::: "memory");
    else
      asm volatile("s_waitcnt vmcnt(0) lgkmcnt(0)" ::: "memory");
    __builtin_amdgcn_s_barrier();
  }

  float* Cf = (float*)Cout;
  __hip_bfloat16* Cb = (__hip_bfloat16*)Cout;
#pragma unroll
  for (int j = 0; j < 4; ++j) {
    int col = bn + wc * 64 + j * 16 + lr;
    float bc = bias[col];
#pragma unroll
    for (int i = 0; i < 4; ++i) {
      int rbase = bm + wr * 64 + i * 16 + kg * 4;
#pragma unroll
      for (int r = 0; r < 4; ++r) {
        float val = acc[i][j][r] + bc;
        if (mode & 1) val = fmaxf(val, 0.0f);
        if (mode < 2) Cf[(size_t)(rbase + r) * N + col] = val;
        else          Cb[(size_t)(rbase + r) * N + col] = __float2bfloat16(val);
      }
    }
  }
}

// ---------------- 256x256 bf16 GEMM, 3-buffer BK=32 counted-vmcnt, fp16 out --------
__global__ __launch_bounds__(512, 2) void gemm256_k(
    const __hip_bfloat16* __restrict__ A,   // [M,K]
    const __hip_bfloat16* __restrict__ Bt,  // [N,K]
    const float* __restrict__ bias,
    __half* __restrict__ C,                 // [M,N] fp16 logits
    int N, int K, int gridM) {
  __shared__ __align__(16) char L[3][32768];   // per buf: A 16KB | B 16KB
  const int tid = threadIdx.x, w = tid >> 6, lane = tid & 63;
  const int wm = w >> 2, wn = w & 3;
  const int lr = lane & 15, kg = lane >> 4;
  const int nwg = gridDim.x, id = blockIdx.x;
  const int swz = (id & 7) * (nwg >> 3) + (id >> 3);
  const int bm = (swz % gridM) * 256, bn = (swz / gridM) * 256;
  const int NT = K >> 5;
  const __hip_bfloat16* Ag = A + (size_t)bm * K;
  const __hip_bfloat16* Bg = Bt + (size_t)bn * K;

  auto stage = [&](int t) {   // 4 loads/thread (A 2 + B 2)
    const int buf = t % 3, k0 = t * 32;
#pragma unroll
    for (int j = 0; j < 2; ++j) {
      int slot = w * 64 + lane + j * 512;          // 0..1023 (16B slots)
      int row = slot >> 2;                         // 0..255
      int cs = (slot & 3) ^ ((row >> 1) & 3);
      GLDS(Ag + (size_t)row * K + k0 + cs * 8, L[buf] + w * 1024 + j * 8192);
      GLDS(Bg + (size_t)row * K + k0 + cs * 8, L[buf] + 16384 + w * 1024 + j * 8192);
    }
  };

  f32x4 acc[8][4] = {};
  stage(0);
  stage(1);
  asm volatile("s_waitcnt vmcnt(4)" ::: "memory");
  __builtin_amdgcn_s_barrier();

  for (int t = 0; t < NT; ++t) {
    const char* buf = L[t % 3];
    if (t + 2 < NT) stage(t + 2);
    bf16x8 af[8], bfr[4];
#pragma unroll
    for (int mg = 0; mg < 8; ++mg) {
      int row = wm * 128 + mg * 16 + lr;
      af[mg] = *(const bf16x8*)(buf + row * 64 + ((kg ^ ((row >> 1) & 3)) << 4));
    }
#pragma unroll
    for (int n = 0; n < 4; ++n) {
      int row = wn * 64 + n * 16 + lr;
      bfr[n] = *(const bf16x8*)(buf + 16384 + row * 64 + ((kg ^ ((row >> 1) & 3)) << 4));
    }
    __builtin_amdgcn_s_setprio(1);
#pragma unroll
    for (int mg = 0; mg < 8; ++mg)
#pragma unroll
      for (int n = 0; n < 4; ++n)
        acc[mg][n] = __builtin_amdgcn_mfma_f32_16x16x32_bf16(af[mg], bfr[n], acc[mg][n], 0, 0, 0);
    __builtin_amdgcn_s_setprio(0);
    if (t + 2 < NT)
      asm volatile("s_waitcnt vmcnt(4) lgkmcnt(0)" ::: "memory");
    else
      asm volatile("s_waitcnt vmcnt(0) lgkmcnt(0)" ::: "memory");
    __builtin_amdgcn_s_barrier();
  }

  // epilogue (fp16)
#pragma unroll
  for (int mg = 0; mg < 8; ++mg) {
    int rbase = bm + wm * 128 + mg * 16 + (kg << 2);
#pragma unroll
    for (int n = 0; n < 4; ++n) {
      int col = bn + (wn << 6) + n * 16 + lr;
      float bc = bias[col];
#pragma unroll
      for (int r = 0; r < 4; ++r)
        C[(size_t)(rbase + r) * N + col] = __float2half(acc[mg][n][r] + bc);
    }
  }
}

// ---------------- MFMA flash attention, 3-buffer counted-vmcnt pipeline ------------
__global__ __launch_bounds__(256) void attn_mfma_k(
    const __hip_bfloat16* __restrict__ q, int sQ,
    const __hip_bfloat16* __restrict__ k, int sK,
    const __hip_bfloat16* __restrict__ vt,   // [(b*H+h)*64 + d][S]
    __hip_bfloat16* __restrict__ o,          // [BS][HD]
    int causal) {
  __shared__ __align__(16) char Ks[3][8192];
  __shared__ __align__(16) char Vs[3][8192];
  __shared__ __align__(16) char Ps[4][2304];   // per-wave P tile [16 q][72 bf16]
  const int tid = threadIdx.x, w = tid >> 6, l = tid & 63;
  const int lr = l & 15, lg = l >> 4;
  const int q0 = blockIdx.x * 64, h = blockIdx.y, b = blockIdx.z;

  const int qrow = q0 + w * 16 + lr;
  const __hip_bfloat16* qp = q + (size_t)(b * kS + qrow) * sQ + h * 64 + lg * 8;
  bf16x8 aQ0 = *(const bf16x8*)qp;
  bf16x8 aQ1 = *(const bf16x8*)(qp + 32);

  f32x4 oacc[4] = {};
  float mrun[4], lrun[4];
#pragma unroll
  for (int r = 0; r < 4; ++r) { mrun[r] = -INFINITY; lrun[r] = 0.0f; }

  const int ntiles = causal ? ((q0 >> 6) + 1) : (kS >> 6);
  const int diagT = causal ? (q0 >> 6) : -1;
  const char* kbase = (const char*)(k + (size_t)(b * kS) * sK + h * 64);
  const char* vbase = (const char*)(vt + (size_t)((b * kH + h) * 64) * kS);
  char* Pw = Ps[w];

  auto stage = [&](int t) {   // 4 loads/thread (K 2 + V 2)
    const int buf = t % 3, kv0 = t * 64;
#pragma unroll
    for (int i = 0; i < 2; ++i) {
      int slot = w * 128 + i * 64 + l;
      int row = slot >> 3, sl = slot & 7, c = sl ^ (row & 7);
      GLDS(kbase + (size_t)(kv0 + row) * sK * 2 + c * 16, Ks[buf] + (w * 128 + i * 64) * 16);
      GLDS(vbase + (size_t)row * kS * 2 + kv0 * 2 + c * 16, Vs[buf] + (w * 128 + i * 64) * 16);
    }
  };

  stage(0);
  if (ntiles > 1) {
    stage(1);
    asm volatile("s_waitcnt vmcnt(4)" ::: "memory");
  } else {
    asm volatile("s_waitcnt vmcnt(0)" ::: "memory");
  }
  __builtin_amdgcn_s_barrier();

  for (int t = 0; t < ntiles; ++t) {
    const int kv0 = t * 64;
    const char* Kb = Ks[t % 3];
    const char* Vb = Vs[t % 3];
    if (t + 2 < ntiles) stage(t + 2);

    // ---- S = Q @ K^T ----
    f32x4 sacc[4] = {};
#pragma unroll
    for (int nf = 0; nf < 4; ++nf) {
      int key = nf * 16 + lr;
#pragma unroll
      for (int kf = 0; kf < 2; ++kf) {
        int ch = (lg + kf * 4) ^ (key & 7);
        bf16x8 bK = *(const bf16x8*)(Kb + key * 128 + ch * 16);
        sacc[nf] = __builtin_amdgcn_mfma_f32_16x16x32_bf16(kf ? aQ1 : aQ0, bK, sacc[nf], 0, 0, 0);
      }
    }

    // ---- online softmax ----
#pragma unroll
    for (int r = 0; r < 4; ++r) {
      int row16 = lg * 4 + r;
      int qg = q0 + w * 16 + row16;
      float sv[4];
#pragma unroll
      for (int nf = 0; nf < 4; ++nf) {
        float s = sacc[nf][r] * 0.125f;
        if (t == diagT && (kv0 + nf * 16 + lr) > qg) s = -INFINITY;
        sv[nf] = s;
      }
      float mx = fmaxf(fmaxf(sv[0], sv[1]), fmaxf(sv[2], sv[3]));
#pragma unroll
      for (int m = 1; m < 16; m <<= 1) mx = fmaxf(mx, __shfl_xor(mx, m));
      float mnew = fmaxf(mrun[r], mx);
      float sc = __expf(mrun[r] - mnew);
      mrun[r] = mnew;
      float rs = 0.0f;
#pragma unroll
      for (int nf = 0; nf < 4; ++nf) {
        float p = __expf(sv[nf] - mnew);
        rs += p;
        *(__hip_bfloat16*)(Pw + row16 * 144 + (nf * 16 + lr) * 2) = __float2bfloat16(p);
      }
#pragma unroll
      for (int m = 1; m < 16; m <<= 1) rs += __shfl_xor(rs, m);
      lrun[r] = lrun[r] * sc + rs;
#pragma unroll
      for (int nfd = 0; nfd < 4; ++nfd) oacc[nfd][r] *= sc;
    }

    // ---- O += P @ V ----
    bf16x8 aP0 = *(const bf16x8*)(Pw + lr * 144 + (lg * 8) * 2);
    bf16x8 aP1 = *(const bf16x8*)(Pw + lr * 144 + (lg * 8 + 32) * 2);
#pragma unroll
    for (int nfd = 0; nfd < 4; ++nfd) {
      int d = nfd * 16 + lr;
#pragma unroll
      for (int kf = 0; kf < 2; ++kf) {
        int ch = (lg + kf * 4) ^ (d & 7);
        bf16x8 bV = *(const bf16x8*)(Vb + d * 128 + ch * 16);
        oacc[nfd] = __builtin_amdgcn_mfma_f32_16x16x32_bf16(kf ? aP1 : aP0, bV, oacc[nfd], 0, 0, 0);
      }
    }

    if (t + 1 < ntiles) {
      if (t + 2 < ntiles)
        asm volatile("s_waitcnt vmcnt(4) lgkmcnt(0)" ::: "memory");
      else
        asm volatile("s_waitcnt vmcnt(0) lgkmcnt(0)" ::: "memory");
      __builtin_amdgcn_s_barrier();
    }
  }

#pragma unroll
  for (int r = 0; r < 4; ++r) {
    float inv = 1.0f / lrun[r];
    int rowg = q0 + w * 16 + lg * 4 + r;
#pragma unroll
    for (int nfd = 0; nfd < 4; ++nfd)
      o[(size_t)(b * kS + rowg) * kHD + h * 64 + nfd * 16 + lr] =
          __float2bfloat16(oacc[nfd][r] * inv);
  }
}

// ---------------- residual + LayerNorm (dual fp32/bf16 out, float4) ----------------
__global__ __launch_bounds__(256) void ln_res_k(const float* __restrict__ a,
                                                const float* __restrict__ b,
                                                const float* __restrict__ gamma,
                                                const float* __restrict__ beta,
                                                float* __restrict__ out,
                                                __hip_bfloat16* __restrict__ outb) {
  __shared__ float sh[10];
  int row = blockIdx.x, tid = threadIdx.x;
  const float4* a4 = (const float4*)(a + (size_t)row * kE);
  const float4* b4 = (const float4*)(b + (size_t)row * kE);
  float4 t = a4[tid], u = b4[tid];
  t.x += u.x; t.y += u.y; t.z += u.z; t.w += u.w;
  float s = t.x + t.y + t.z + t.w;
  float q2 = t.x * t.x + t.y * t.y + t.z * t.z + t.w * t.w;
  for (int o = 32; o > 0; o >>= 1) { s += __shfl_down(s, o); q2 += __shfl_down(q2, o); }
  int lane = tid & 63, wid = tid >> 6;
  if (lane == 0) { sh[wid] = s; sh[4 + wid] = q2; }
  __syncthreads();
  if (tid == 0) {
    float S2 = sh[0] + sh[1] + sh[2] + sh[3];
    float Q2 = sh[4] + sh[5] + sh[6] + sh[7];
    float mean = S2 * (1.0f / kE);
    float var = Q2 * (1.0f / kE) - mean * mean;
    sh[8] = mean;
    sh[9] = rsqrtf(var + 1e-15f);
  }
  __syncthreads();
  float mean = sh[8], inv = sh[9];
  float4 g = ((const float4*)gamma)[tid], be = ((const float4*)beta)[tid];
  float4 v;
  v.x = g.x * ((t.x - mean) * inv) + be.x;
  v.y = g.y * ((t.y - mean) * inv) + be.y;
  v.z = g.z * ((t.z - mean) * inv) + be.z;
  v.w = g.w * ((t.w - mean) * inv) + be.w;
  ((float4*)(out + (size_t)row * kE))[tid] = v;
  union { __hip_bfloat16 h[4]; short4 s4; } uo;
  uo.h[0] = __float2bfloat16(v.x); uo.h[1] = __float2bfloat16(v.y);
  uo.h[2] = __float2bfloat16(v.z); uo.h[3] = __float2bfloat16(v.w);
  ((short4*)(outb + (size_t)row * kE))[tid] = uo.s4;
}

// ---------------- row softmax: fp16 logits -> fp32 probs ----------------
__global__ __launch_bounds__(512) void softmax_rows_k(const __half* __restrict__ lgt,
                                                      float* __restrict__ out) {
  __shared__ float sh[18];
  int row = blockIdx.x;
  const u16x8* x8 = (const u16x8*)(lgt + (size_t)row * kV);
  const int n8 = kV / 8;   // 4000
  int tid = threadIdx.x;
  u16x8 v[8];
  float m = -INFINITY, sum = 0.0f;
#pragma unroll
  for (int i = 0; i < 8; ++i) {
    int idx = tid + i * 512;
    if (idx < n8) {
      v[i] = x8[idx];
      union { u16x8 u; __half h[8]; } cv; cv.u = v[i];
      float f[8];
#pragma unroll
      for (int j = 0; j < 8; ++j) f[j] = __half2float(cv.h[j]);
      float mx = f[0];
#pragma unroll
      for (int j = 1; j < 8; ++j) mx = fmaxf(mx, f[j]);
      float nm = fmaxf(m, mx);
      float add = 0.0f;
#pragma unroll
      for (int j = 0; j < 8; ++j) add += __expf(f[j] - nm);
      sum = sum * __expf(m - nm) + add;
      m = nm;
    }
  }
  for (int o = 32; o > 0; o >>= 1) {
    float om = __shfl_down(m, o), os = __shfl_down(sum, o);
    float nm = fmaxf(m, om);
    sum = sum * __expf(m - nm) + os * __expf(om - nm);
    m = nm;
  }
  int lane = tid & 63, wid = tid >> 6;
  if (lane == 0) { sh[wid] = m; sh[8 + wid] = sum; }
  __syncthreads();
  if (tid == 0) {
    float M = sh[0], S2 = 0.0f;
#pragma unroll
    for (int i2 = 1; i2 < 8; ++i2) M = fmaxf(M, sh[i2]);
#pragma unroll
    for (int i2 = 0; i2 < 8; ++i2) S2 += sh[8 + i2] * __expf(sh[i2] - M);
    sh[16] = M;
    sh[17] = 1.0f / S2;
  }
  __syncthreads();
  float M = sh[16], rcp = sh[17];
#pragma unroll
  for (int i = 0; i < 8; ++i) {
    int idx = tid + i * 512;
    if (idx < n8) {
      union { u16x8 u; __half h[8]; } cv; cv.u = v[i];
      float4 o0, o1;
      o0.x = __expf(__half2float(cv.h[0]) - M) * rcp;
      o0.y = __expf(__half2float(cv.h[1]) - M) * rcp;
      o0.z = __expf(__half2float(cv.h[2]) - M) * rcp;
      o0.w = __expf(__half2float(cv.h[3]) - M) * rcp;
      o1.x = __expf(__half2float(cv.h[4]) - M) * rcp;
      o1.y = __expf(__half2float(cv.h[5]) - M) * rcp;
      o1.z = __expf(__half2float(cv.h[6]) - M) * rcp;
      o1.w = __expf(__half2float(cv.h[7]) - M) * rcp;
      float* dst = out + (size_t)row * kV + idx * 8;
      ((float4*)dst)[0] = o0;
      ((float4*)dst)[1] = o1;
    }
  }
}

}  // namespace

extern "C" void kernel_launch(void* const* d_in, const int* in_sizes, int n_in,
                              void* d_out, int out_size, void* d_ws, size_t ws_size,
                              hipStream_t stream) {
  const int*   src    = (const int*)d_in[0];
  const int*   trg    = (const int*)d_in[1];
  const float* emb_e  = (const float*)d_in[2];
  const float* emb_d  = (const float*)d_in[3];
  const float* qkv_e  = (const float*)d_in[4];
  const float* bqkv_e = (const float*)d_in[5];
  const float* wo_e   = (const float*)d_in[6];
  const float* bo_e   = (const float*)d_in[7];
  const float* qkv_m  = (const float*)d_in[8];
  const float* bqkv_m = (const float*)d_in[9];
  const float* wo_m   = (const float*)d_in[10];
  const float* bo_m   = (const float*)d_in[11];
  const float* qkv_c  = (const float*)d_in[12];
  const float* bqkv_c = (const float*)d_in[13];
  const float* wo_c   = (const float*)d_in[14];
  const float* bo_c   = (const float*)d_in[15];
  const float* gamma  = (const float*)d_in[16];
  const float* beta   = (const float*)d_in[17];
  const float* ffw1   = (const float*)d_in[18];
  const float* ffb1   = (const float*)d_in[19];
  const float* ffw2   = (const float*)d_in[20];
  const float* ffb2   = (const float*)d_in[21];
  const float* wout   = (const float*)d_in[22];
  const float* bout   = (const float*)d_in[23];
  float* out = (float*)d_out;

  char* base = (char*)d_ws;
  const size_t R = (size_t)kBS * kE;   // 2M elements
  // ---- zone A (dead by the time logits are written; overlapped by lgt) ----
  float* enc_x = (float*)base;         // R, reused as n2d
  float* dec_x = enc_x + R;            // R, reused as n3d (dead after final ln)
  float* t1    = dec_x + R;
  float* n1    = t1 + R;               // reused as n1d
  float* n_enc = n1 + R;
  __hip_bfloat16* bb     = (__hip_bfloat16*)(n_enc + R);
  __hip_bfloat16* enc_xb = bb;                       // R
  __hip_bfloat16* n1b    = enc_xb + R;               // R
  __hip_bfloat16* n_encb = n1b + R;                  // R
  __hip_bfloat16* qkvb   = n_encb + R;               // 3R   [BS, 3HD]
  __hip_bfloat16* kvb    = qkvb + 3 * R;             // 2R   [BS, 2HD]
  __hip_bfloat16* qb1    = kvb + 2 * R;              // R    [BS, HD]
  __hip_bfloat16* vtb    = qb1 + R;                  // R    [B*H*64, S]
  __hip_bfloat16* ao16   = vtb + R;                  // R
  __hip_bfloat16* ffhb   = ao16 + R;                 // R/2
  __hip_bfloat16* Wqkv   = ffhb + R / 2;             // 3M  [3HD, E]
  __hip_bfloat16* Wo     = Wqkv + (size_t)3 * kHD * kE;  // 1M
  __hip_bfloat16* Wf1 = Wo + (size_t)kE * kHD;       // [FH, E]
  __hip_bfloat16* Wf2 = Wf1 + (size_t)kFH * kE;      // [E, FH]
  // ---- zone B (live at logits time) ----
  const size_t lgtBytes = (size_t)kBS * kV * sizeof(__half);   // 131 MB
  __hip_bfloat16* dec_xb = (__hip_bfloat16*)(base + lgtBytes); // R
  __hip_bfloat16* Wv     = dec_xb + R;                         // [V, E]
  __half* lgt = (__half*)base;        // overlaps zone A only
  float* pe = (float*)Wv;             // alias: PE table used before Wv is written

  auto tcast = [&](const float* s, __hip_bfloat16* d, int Rr, int Cc, int batch) {
    tcast_k<<<dim3(Cc / 32, Rr / 32, batch), 256, 0, stream>>>(s, d, Rr, Cc);
  };
  auto gemmb = [&](const __hip_bfloat16* A, const __hip_bfloat16* Bt, const float* bias,
                   void* C, int M, int N, int K, int mode) {
    int gridM = M / 128;
    gemm_bf16_k<<<dim3(gridM * (N / 128)), 256, 0, stream>>>(A, Bt, bias, C, N, K, mode, gridM);
  };
  auto vtrans = [&](const __hip_bfloat16* v, int sV) {
    vtrans_k<<<dim3(kS / 32, kD / 32, kB * kH), 256, 0, stream>>>(v, sV, vtb);
  };
  auto attn = [&](const __hip_bfloat16* q, int sQ, const __hip_bfloat16* k, int sK,
                  int causal) {
    attn_mfma_k<<<dim3(kS / 64, kH, kB), 256, 0, stream>>>(q, sQ, k, sK, vtb, ao16, causal);
  };
  auto ln = [&](const float* a, const float* b2, int sel, float* o1, __hip_bfloat16* o2) {
    ln_res_k<<<kBS, 256, 0, stream>>>(a, b2, gamma + sel * kE, beta + sel * kE, o1, o2);
  };

  pe_table_k<<<kS, 256, 0, stream>>>(pe);

  // ---------------- encoder ----------------
  embed_pe_k<<<kBS, 256, 0, stream>>>(src, emb_e, pe, enc_x, enc_xb);
  tcast(qkv_e, Wqkv, kE, kD, 3 * kH);
  tcast(wo_e, Wo, kHD, kE, 1);
  gemmb(enc_xb, Wqkv, bqkv_e, qkvb, kBS, 3 * kHD, kE, 2);
  vtrans(qkvb + 2 * kHD, 3 * kHD);
  attn(qkvb, 3 * kHD, qkvb + kHD, 3 * kHD, 0);
  gemmb(ao16, Wo, bo_e, t1, kBS, kE, kHD, 0);
  ln(enc_x, t1, 0, n1, n1b);
  tcast(ffw1, Wf1, kE, kFH, 1);
  tcast(ffw2, Wf2, kFH, kE, 1);
  gemmb(n1b, Wf1, ffb1, ffhb, kBS, kFH, kE, 3);
  gemmb(ffhb, Wf2, ffb2, t1, kBS, kE, kFH, 0);
  ln(n1, t1, 1, n_enc, n_encb);

  // ---------------- decoder ----------------
  embed_pe_k<<<kBS, 256, 0, stream>>>(trg, emb_d, pe, dec_x, dec_xb);
  tcast(qkv_m, Wqkv, kE, kD, 3 * kH);
  tcast(wo_m, Wo, kHD, kE, 1);
  gemmb(dec_xb, Wqkv, bqkv_m, qkvb, kBS, 3 * kHD, kE, 2);
  vtrans(qkvb + 2 * kHD, 3 * kHD);
  attn(qkvb, 3 * kHD, qkvb + kHD, 3 * kHD, 1);
  gemmb(ao16, Wo, bo_m, t1, kBS, kE, kHD, 0);
  ln(dec_x, t1, 2, n1, n1b);   // n1d

  tcast(qkv_c, Wqkv, kE, kD, 3 * kH);
  tcast(wo_c, Wo, kHD, kE, 1);
  gemmb(n1b, Wqkv, bqkv_c, qb1, kBS, kHD, kE, 2);
  gemmb(n_encb, Wqkv + (size_t)kHD * kE, bqkv_c + kHD, kvb, kBS, 2 * kHD, kE, 2);
  vtrans(kvb + kHD, 2 * kHD);
  attn(qb1, kHD, kvb, 2 * kHD, 0);
  gemmb(ao16, Wo, bo_c, t1, kBS, kE, kHD, 0);
  ln(n1, t1, 3, enc_x, enc_xb);  // n2d

  tcast(ffw1 + (size_t)kE * kFH, Wf1, kE, kFH, 1);
  tcast(ffw2 + (size_t)kFH * kE, Wf2, kFH, kE, 1);
  gemmb(enc_xb, Wf1, ffb1 + kFH, ffhb, kBS, kFH, kE, 3);
  gemmb(ffhb, Wf2, ffb2 + kE, t1, kBS, kE, kFH, 0);
  ln(enc_x, t1, 4, dec_x, dec_xb);  // n3d

  // ---------------- logits (fp16) + softmax (fp16 -> fp32) ----------------
  tcast(wout, Wv, kE, kV, 1);
  gemm256_k<<<dim3((kBS / 256) * (kV / 256)), 512, 0, stream>>>(
      dec_xb, Wv, bout, lgt, kV, kE, kBS / 256);
  softmax_rows_k<<<kBS, 512, 0, stream>>>(lgt, out);
}